// Round 3
// baseline (158.037 us; speedup 1.0000x reference)
//
#include <hip/hip_runtime.h>

// ImplicitModelLoRA: X = relu(s*L*(R^T X) + B U^T) iterated; out = (C X + D U^T)^T
// k_iter: 256 blocks (1 column each); L fp32 + R bf16 fully register-resident.
// Round-3 fixes: __launch_bounds__(512,1) (round 2's (512,2) capped VGPR at 128
// -> spilled 16MB/dispatch to scratch); 4-way accumulator ILP; NIT=8.

#define NIT 8

// ws float-offset layout
#define WS_NORML   0                    // atomicMax (int bits) of ||L||inf
#define WS_COLSUM  1                    // [64] atomicAdd partials of ||R^T||inf
#define WS_LP      80                   // 65536 f32: packed L
#define WS_RPK     (WS_LP + 65536)      // 32768 u32: packed bf16 R pairs
#define WS_BUT     (WS_RPK + 32768)     // 262144 f32: (B@U^T)^T  [m][n]
#define WS_XT      (WS_BUT + 262144)    // 262144 f32: X^T        [m][n]

__device__ __forceinline__ unsigned f2bf(float x) {  // RNE f32->bf16 bits
  unsigned b = __float_as_uint(x);
  return (b + 0x7FFFu + ((b >> 16) & 1u)) >> 16;
}

// ---- K1: pack L/R + norms (blocks 0..159) and BUt GEMM (blocks 160..415) -
// BUt[m][n] = sum_p B[n][p] U[m][p], 32x32 tiles, swizzled LDS.
__global__ __launch_bounds__(256) void k_prep(const float* __restrict__ L,
                                              const float* __restrict__ R,
                                              const float* __restrict__ B,
                                              const float* __restrict__ U,
                                              float* __restrict__ ws) {
  __shared__ __align__(16) float Us[32 * 32], Bs[32 * 32];
  int b = blockIdx.x, t = threadIdx.x;
  if (b < 128) {                                   // pack L (f32) + R (bf16)
    int base = b * 256 + t;                        // 0..32767
#pragma unroll
    for (int h = 0; h < 2; ++h) {
      int f = base + h * 32768;
      int j = f & 3, ln = (f >> 2) & 63, k4 = (f >> 8) & 15, g = f >> 12;
      ws[WS_LP + f] = L[(g * 64 + ln) * 64 + k4 * 4 + j];
    }
    {
      int u = base;
      int jj = u & 3, k = (u >> 2) & 63, j4 = (u >> 8) & 15, w = u >> 12;
      int r0 = 128 * w + 8 * j4 + 2 * jj;
      unsigned pl = f2bf(R[r0 * 64 + k]);
      unsigned ph = f2bf(R[(r0 + 1) * 64 + k]);
      ((unsigned*)ws)[WS_RPK + u] = pl | (ph << 16);
    }
  } else if (b < 144) {                            // ||L||inf partials
    int rb = (b - 128) * 64;
    int row = rb + (t >> 2), c0 = (t & 3) * 16;
    float sum = 0.f;
#pragma unroll
    for (int c = 0; c < 16; ++c) sum += fabsf(L[row * 64 + c0 + c]);
    sum += __shfl_xor(sum, 1);
    sum += __shfl_xor(sum, 2);
#pragma unroll
    for (int m = 32; m; m >>= 1) sum = fmaxf(sum, __shfl_xor(sum, m));
    if ((t & 63) == 0) atomicMax((int*)ws + WS_NORML, __float_as_int(sum));
  } else if (b < 160) {                            // ||R^T||inf col-sum partials
    int rb = (b - 144) * 64;
    int k = t & 63, rg = t >> 6;
    float sum = 0.f;
#pragma unroll
    for (int r = 0; r < 16; ++r) sum += fabsf(R[(rb + rg * 16 + r) * 64 + k]);
    atomicAdd(ws + WS_COLSUM + k, sum);
  } else {                                         // BUt 32x32 tile
    int idx = b - 160;
    int n0 = (idx & 31) * 32, m0 = (idx >> 5) * 32;
    int ti = t & 15, tj = t >> 4;
    int lr = t >> 3, lc = t & 7;
    float4* Us4 = (float4*)Us;
    float4* Bs4 = (float4*)Bs;
    const float4* U4 = (const float4*)U;
    const float4* B4 = (const float4*)B;
    float acc00 = 0, acc01 = 0, acc10 = 0, acc11 = 0;
    for (int kc = 0; kc < 16; ++kc) {
      __syncthreads();
      Us4[lr * 8 + (lc ^ (lr & 7))] = U4[(m0 + lr) * 128 + kc * 8 + lc];
      Bs4[lr * 8 + (lc ^ (lr & 7))] = B4[(n0 + lr) * 128 + kc * 8 + lc];
      __syncthreads();
#pragma unroll
      for (int k4 = 0; k4 < 8; ++k4) {
        float4 u0 = Us4[tj * 8 + (k4 ^ (tj & 7))];
        float4 u1 = Us4[(tj + 16) * 8 + (k4 ^ (tj & 7))];
        float4 b0 = Bs4[ti * 8 + (k4 ^ (ti & 7))];
        float4 b1 = Bs4[(ti + 16) * 8 + (k4 ^ (ti & 7))];
        acc00 += u0.x * b0.x + u0.y * b0.y + u0.z * b0.z + u0.w * b0.w;
        acc01 += u0.x * b1.x + u0.y * b1.y + u0.z * b1.z + u0.w * b1.w;
        acc10 += u1.x * b0.x + u1.y * b0.y + u1.z * b0.z + u1.w * b0.w;
        acc11 += u1.x * b1.x + u1.y * b1.y + u1.z * b1.z + u1.w * b1.w;
      }
    }
    float* BUt = ws + WS_BUT;
    BUt[(m0 + tj) * 1024 + n0 + ti] = acc00;
    BUt[(m0 + tj) * 1024 + n0 + ti + 16] = acc01;
    BUt[(m0 + tj + 16) * 1024 + n0 + ti] = acc10;
    BUt[(m0 + tj + 16) * 1024 + n0 + ti + 16] = acc11;
  }
}

// ---- K2: fixed-point loop, matrices register-resident --------------------
__global__ __launch_bounds__(512, 1) void k_iter(float* __restrict__ ws) {
  __shared__ __align__(16) float x_s[1024];
  __shared__ __align__(16) float t_s[64];
  __shared__ __align__(16) float tpart[8][64];
  int tid = threadIdx.x, w = tid >> 6, lane = tid & 63;
  int c = blockIdx.x;
  float nL = __int_as_float(((const int*)ws)[WS_NORML]);
  float nR = ws[WS_COLSUM + lane];
#pragma unroll
  for (int m = 32; m; m >>= 1) nR = fmaxf(nR, __shfl_xor(nR, m));
  float s = (nL > 0.97f ? 0.97f / nL : 1.f) * (nR > 0.97f ? 0.97f / nR : 1.f);
  const float4* Lp4 = (const float4*)(ws + WS_LP);
  const uint4* Rp4 = (const uint4*)(ws + WS_RPK);
  float4 Lr0[16], Lr1[16];
  uint4 Rr[16];
#pragma unroll
  for (int j = 0; j < 16; ++j) Lr0[j] = Lp4[(w * 16 + j) * 64 + lane];
#pragma unroll
  for (int j = 0; j < 16; ++j) Lr1[j] = Lp4[((w + 8) * 16 + j) * 64 + lane];
#pragma unroll
  for (int j = 0; j < 16; ++j) Rr[j] = Rp4[(w * 16 + j) * 64 + lane];
  const float* BUt = ws + WS_BUT;
  float bu0 = BUt[c * 1024 + tid];
  float bu1 = BUt[c * 1024 + 512 + tid];
  float a0 = fmaxf(bu0, 0.f), a1 = fmaxf(bu1, 0.f);
  x_s[tid] = a0;
  x_s[512 + tid] = a1;
  __syncthreads();
  for (int it = 0; it < NIT - 1; ++it) {
    // phase 2: tpart[w][k] = sum over wave's 128 rows of R[n][k]*x[n]; 4-acc ILP
    float tp0 = 0.f, tp1 = 0.f, tp2 = 0.f, tp3 = 0.f;
    const float4* x4 = (const float4*)x_s;
#pragma unroll
    for (int j4 = 0; j4 < 16; ++j4) {
      float4 xa = x4[w * 32 + 2 * j4];
      float4 xb = x4[w * 32 + 2 * j4 + 1];
      uint4 rv = Rr[j4];
      tp0 = fmaf(__uint_as_float(rv.x << 16), xa.x, tp0);
      tp1 = fmaf(__uint_as_float(rv.x & 0xFFFF0000u), xa.y, tp1);
      tp2 = fmaf(__uint_as_float(rv.y << 16), xa.z, tp2);
      tp3 = fmaf(__uint_as_float(rv.y & 0xFFFF0000u), xa.w, tp3);
      tp0 = fmaf(__uint_as_float(rv.z << 16), xb.x, tp0);
      tp1 = fmaf(__uint_as_float(rv.z & 0xFFFF0000u), xb.y, tp1);
      tp2 = fmaf(__uint_as_float(rv.w << 16), xb.z, tp2);
      tp3 = fmaf(__uint_as_float(rv.w & 0xFFFF0000u), xb.w, tp3);
    }
    tpart[w][lane] = (tp0 + tp1) + (tp2 + tp3);
    __syncthreads();
    if (tid < 64) {
      float tsum = 0.f;
#pragma unroll
      for (int g = 0; g < 8; ++g) tsum += tpart[g][tid];
      t_s[tid] = s * tsum;
    }
    __syncthreads();
    // phase 1: x = relu(L t + bu), rows tid and tid+512; 4-acc ILP
    const float4* t4 = (const float4*)t_s;
    float b0a = bu0, b0b = 0.f, b1a = bu1, b1b = 0.f;
#pragma unroll
    for (int k4 = 0; k4 < 8; ++k4) {
      float4 tv = t4[k4];
      float4 l0 = Lr0[k4], l1 = Lr1[k4];
      b0a += l0.x * tv.x + l0.y * tv.y + l0.z * tv.z + l0.w * tv.w;
      b1a += l1.x * tv.x + l1.y * tv.y + l1.z * tv.z + l1.w * tv.w;
    }
#pragma unroll
    for (int k4 = 8; k4 < 16; ++k4) {
      float4 tv = t4[k4];
      float4 l0 = Lr0[k4], l1 = Lr1[k4];
      b0b += l0.x * tv.x + l0.y * tv.y + l0.z * tv.z + l0.w * tv.w;
      b1b += l1.x * tv.x + l1.y * tv.y + l1.z * tv.z + l1.w * tv.w;
    }
    a0 = fmaxf(b0a + b0b, 0.f);
    a1 = fmaxf(b1a + b1b, 0.f);
    x_s[tid] = a0;
    x_s[512 + tid] = a1;
    __syncthreads();
  }
  float* Xt = ws + WS_XT;
  Xt[c * 1024 + tid] = a0;
  Xt[c * 1024 + 512 + tid] = a1;
}

// ---- K3: out[m][q] = sum_n C[q][n] Xt[m][n] + sum_p D[q][p] U[m][p] ------
__global__ __launch_bounds__(256) void k_epi(const float* __restrict__ C,
                                             const float* __restrict__ D,
                                             const float* __restrict__ U,
                                             const float* __restrict__ ws,
                                             float* __restrict__ out) {
  __shared__ __align__(16) float As[32 * 32], Bs[32 * 32];
  int t = threadIdx.x;
  int q0 = blockIdx.x * 32, m0 = blockIdx.y * 32, z = blockIdx.z;
  const float* Ap;
  const float* Bp;
  int sd4, koff4;
  if (z < 2) { Ap = C; Bp = ws + WS_XT; sd4 = 256; koff4 = z * 128; }
  else       { Ap = D; Bp = U;          sd4 = 128; koff4 = 0; }
  int ti = t & 15, tj = t >> 4;
  int lr = t >> 3, lc = t & 7;
  float4* As4 = (float4*)As;
  float4* Bs4 = (float4*)Bs;
  const float4* A4 = (const float4*)Ap;
  const float4* B4 = (const float4*)Bp;
  float acc00 = 0, acc01 = 0, acc10 = 0, acc11 = 0;
  for (int kc = 0; kc < 16; ++kc) {
    __syncthreads();
    As4[lr * 8 + (lc ^ (lr & 7))] = A4[(q0 + lr) * sd4 + koff4 + kc * 8 + lc];
    Bs4[lr * 8 + (lc ^ (lr & 7))] = B4[(m0 + lr) * sd4 + koff4 + kc * 8 + lc];
    __syncthreads();
#pragma unroll
    for (int k4 = 0; k4 < 8; ++k4) {
      float4 a0 = As4[ti * 8 + (k4 ^ (ti & 7))];
      float4 a1 = As4[(ti + 16) * 8 + (k4 ^ (ti & 7))];
      float4 b0 = Bs4[tj * 8 + (k4 ^ (tj & 7))];
      float4 b1 = Bs4[(tj + 16) * 8 + (k4 ^ (tj & 7))];
      acc00 += a0.x * b0.x + a0.y * b0.y + a0.z * b0.z + a0.w * b0.w;
      acc01 += a0.x * b1.x + a0.y * b1.y + a0.z * b1.z + a0.w * b1.w;
      acc10 += a1.x * b0.x + a1.y * b0.y + a1.z * b0.z + a1.w * b0.w;
      acc11 += a1.x * b1.x + a1.y * b1.y + a1.z * b1.z + a1.w * b1.w;
    }
  }
  atomicAdd(&out[(m0 + tj) * 256 + q0 + ti], acc00);
  atomicAdd(&out[(m0 + tj + 16) * 256 + q0 + ti], acc01);
  atomicAdd(&out[(m0 + tj) * 256 + q0 + ti + 16], acc10);
  atomicAdd(&out[(m0 + tj + 16) * 256 + q0 + ti + 16], acc11);
}

extern "C" void kernel_launch(void* const* d_in, const int* in_sizes, int n_in,
                              void* d_out, int out_size, void* d_ws, size_t ws_size,
                              hipStream_t stream) {
  const float* U = (const float*)d_in[0];
  const float* L = (const float*)d_in[1];
  const float* R = (const float*)d_in[2];
  const float* B = (const float*)d_in[3];
  const float* C = (const float*)d_in[4];
  const float* D = (const float*)d_in[5];
  float* ws = (float*)d_ws;
  float* out = (float*)d_out;
  hipMemsetAsync(ws, 0, 80 * sizeof(float), stream);      // norm scratch
  hipMemsetAsync(out, 0, 256 * 256 * sizeof(float), stream);
  hipLaunchKernelGGL(k_prep, dim3(416), dim3(256), 0, stream, L, R, B, U, ws);
  hipLaunchKernelGGL(k_iter, dim3(256), dim3(512), 0, stream, ws);
  hipLaunchKernelGGL(k_epi, dim3(8, 8, 3), dim3(256), 0, stream, C, D, U, ws, out);
}